// Round 2
// baseline (1165.087 us; speedup 1.0000x reference)
//
#include <hip/hip_runtime.h>

// Problem constants (from reference)
#define BATCH 2048
#define T 512
#define NF 10
#define HID 30
#define S3T 1536          // 3*T sequence length after reshape/transpose
#define FEAT_PER_B 15360  // T*30 floats per batch element
// Workspace needed: BATCH * FEAT_PER_B * 4 = 125,829,120 bytes (fp32 feat)

__device__ __forceinline__ float fexp(float x) {
    return __builtin_amdgcn_exp2f(x * 1.44269504088896f);  // v_exp_f32
}
__device__ __forceinline__ float frcp(float x) {
    return __builtin_amdgcn_rcpf(x);                        // v_rcp_f32
}
__device__ __forceinline__ float sigmoid_(float x) {
    return frcp(1.0f + fexp(-x));
}
__device__ __forceinline__ float tanh_(float x) {
    // tanh(x) = 2/(1+exp(-2x)) - 1 ; saturates correctly at +-1 via inf->rcp->0
    return 2.0f * frcp(1.0f + fexp(-2.0f * x)) - 1.0f;
}

// Kernel 1: materialize featflat[b][t*30+c] = concat(e_i, e_j, rbf)
__global__ void feat_kernel(const int* __restrict__ atom_i,
                            const int* __restrict__ atom_j,
                            const float* __restrict__ dist,
                            const float* __restrict__ emb,
                            float* __restrict__ feat) {
    int gid = blockIdx.x * blockDim.x + threadIdx.x;
    const int total = BATCH * FEAT_PER_B;  // 31,457,280 < 2^31
    if (gid >= total) return;
    int b = gid / FEAT_PER_B;
    int r = gid - b * FEAT_PER_B;
    int t = r / 30;
    int c = r - t * 30;
    int bt = b * T + t;
    float v;
    if (c < 10) {
        int ai = atom_i[bt];
        v = (ai != 0) ? emb[ai * NF + c] : 0.0f;
    } else if (c < 20) {
        int aj = atom_j[bt];
        v = (aj != 0) ? emb[aj * NF + (c - 10)] : 0.0f;
    } else {
        int ai = atom_i[bt];
        float d = dist[bt];
        float ctr = (float)(c - 19) * 0.7f;  // centers = (1..10)*0.7
        float diff = ctr - d;
        v = (ai != 0) ? fexp(-diff * diff) : 0.0f;  // GAMMA = 1.0
    }
    feat[gid] = v;
}

// Kernel 2: the GRU recurrence. One wave per block; lanes 0-29 -> batch 2*blk,
// lanes 32-61 -> batch 2*blk+1. Lane = one hidden unit (3 gate rows).
// __launch_bounds__(64,1): allow up to 512 VGPRs (we hold ~120 weight regs).
__launch_bounds__(64, 1)
__global__ void gru_kernel(const float* __restrict__ feat,
                           const float* __restrict__ W_ih,   // [90,10]
                           const float* __restrict__ W_hh,   // [90,30]
                           const float* __restrict__ b_ih,   // [90]
                           const float* __restrict__ b_hh,   // [90]
                           const float* __restrict__ W_out,  // [1,30]
                           const float* __restrict__ b_out,  // [1]
                           float* __restrict__ out) {
    __shared__ float hbuf[64];
    const int lane = threadIdx.x;
    const int half = lane >> 5;        // 0 or 1
    const int base = half << 5;        // LDS base of my half's h
    const int k = lane & 31;
    const bool active = (k < HID);
    const int kk = active ? k : (HID - 1);  // clamp; inactive lanes contribute 0
    const int b = blockIdx.x * 2 + half;

    // Preload weights into VGPRs (fully unrolled -> registers)
    float wih_r[NF], wih_z[NF], wih_n[NF];
#pragma unroll
    for (int d = 0; d < NF; ++d) {
        wih_r[d] = W_ih[(0 * HID + kk) * NF + d];
        wih_z[d] = W_ih[(1 * HID + kk) * NF + d];
        wih_n[d] = W_ih[(2 * HID + kk) * NF + d];
    }
    float whh_r[HID], whh_z[HID], whh_n[HID];
#pragma unroll
    for (int j = 0; j < HID; ++j) {
        whh_r[j] = W_hh[(0 * HID + kk) * HID + j];
        whh_z[j] = W_hh[(1 * HID + kk) * HID + j];
        whh_n[j] = W_hh[(2 * HID + kk) * HID + j];
    }
    const float brz_r = b_ih[0 * HID + kk] + b_hh[0 * HID + kk];
    const float brz_z = b_ih[1 * HID + kk] + b_hh[1 * HID + kk];
    const float bi_n = b_ih[2 * HID + kk];  // n-gate biases must stay split:
    const float bh_n = b_hh[2 * HID + kk];  // n = tanh(i_n + r*(Whh_n@h + b_hh_n))

    const float* xp = feat + (long)b * FEAT_PER_B;

    float h = 0.0f;
    hbuf[lane] = 0.0f;
    __syncthreads();

    // Prefetch x for step 0
    float xc[NF];
#pragma unroll
    for (int d = 0; d < NF; ++d) xc[d] = xp[d * S3T];

    for (int s = 0; s < S3T; ++s) {
        // Prefetch next step's x (hides global-load latency at 1 wave/SIMD)
        float xn[NF];
        const int sn = (s + 1 < S3T) ? (s + 1) : s;
#pragma unroll
        for (int d = 0; d < NF; ++d) xn[d] = xp[d * S3T + sn];

        float ar = brz_r, az = brz_z, ain = bi_n, ahn = bh_n;
#pragma unroll
        for (int d = 0; d < NF; ++d) {
            ar += wih_r[d] * xc[d];
            az += wih_z[d] * xc[d];
            ain += wih_n[d] * xc[d];
        }
#pragma unroll
        for (int j = 0; j < HID; ++j) {
            float hj = hbuf[base + j];  // ds_read_b32 w/ imm offset, broadcast
            ar += whh_r[j] * hj;
            az += whh_z[j] * hj;
            ahn += whh_n[j] * hj;
        }
        float rg = sigmoid_(ar);
        float zg = sigmoid_(az);
        float ng = tanh_(ain + rg * ahn);
        h = ng + zg * (h - ng);  // (1-z)*n + z*h

        __syncthreads();   // reads done before overwrite (cheap: 1 wave/block)
        hbuf[lane] = h;
        __syncthreads();   // write visible before next step's reads

#pragma unroll
        for (int d = 0; d < NF; ++d) xc[d] = xn[d];
    }

    // Output: relu(h . W_out + b_out), reduce over the 30 lanes of my half
    float wout = active ? W_out[kk] : 0.0f;
    float v = h * wout;
#pragma unroll
    for (int off = 16; off; off >>= 1) v += __shfl_down(v, off, 32);
    if (k == 0) {
        float o = v + b_out[0];
        out[b] = o > 0.0f ? o : 0.0f;
    }
}

extern "C" void kernel_launch(void* const* d_in, const int* in_sizes, int n_in,
                              void* d_out, int out_size, void* d_ws, size_t ws_size,
                              hipStream_t stream) {
    const int* atom_i   = (const int*)d_in[0];
    const int* atom_j   = (const int*)d_in[1];
    const float* dist   = (const float*)d_in[2];
    const float* emb    = (const float*)d_in[3];
    const float* W_ih   = (const float*)d_in[4];
    const float* W_hh   = (const float*)d_in[5];
    const float* b_ih   = (const float*)d_in[6];
    const float* b_hh   = (const float*)d_in[7];
    const float* W_out  = (const float*)d_in[8];
    const float* b_out  = (const float*)d_in[9];
    float* out = (float*)d_out;
    float* feat = (float*)d_ws;  // needs 125,829,120 B

    const int total = BATCH * FEAT_PER_B;
    const int threads = 256;
    const int blocks = (total + threads - 1) / threads;
    feat_kernel<<<blocks, threads, 0, stream>>>(atom_i, atom_j, dist, emb, feat);
    gru_kernel<<<BATCH / 2, 64, 0, stream>>>(feat, W_ih, W_hh, b_ih, b_hh,
                                             W_out, b_out, out);
}

// Round 3
// 1029.510 us; speedup vs baseline: 1.1317x; 1.1317x over previous
//
#include <hip/hip_runtime.h>

// Problem constants (from reference)
#define BATCH 2048
#define T 512
#define NF 10
#define HID 30
#define S3T 1536          // 3*T sequence length after reshape/transpose
#define FEAT_PER_B 15360  // T*30 floats per batch element
// Workspace: BATCH * FEAT_PER_B * 4 = 125,829,120 bytes (fp32 feat)

__device__ __forceinline__ float fexp(float x) {
    return __builtin_amdgcn_exp2f(x * 1.44269504088896f);  // v_exp_f32
}
__device__ __forceinline__ float frcp(float x) {
    return __builtin_amdgcn_rcpf(x);                        // v_rcp_f32
}
__device__ __forceinline__ float sigmoid_(float x) {
    return frcp(1.0f + fexp(-x));
}
__device__ __forceinline__ float tanh_(float x) {
    return 2.0f * frcp(1.0f + fexp(-2.0f * x)) - 1.0f;
}

// Kernel 1: materialize featflat[b][t*30+c] = concat(e_i, e_j, rbf)
// (element i = d*1536+s of the reshaped view corresponds to t=i/30, c=i%30)
__global__ void feat_kernel(const int* __restrict__ atom_i,
                            const int* __restrict__ atom_j,
                            const float* __restrict__ dist,
                            const float* __restrict__ emb,
                            float* __restrict__ feat) {
    int gid = blockIdx.x * blockDim.x + threadIdx.x;
    const int total = BATCH * FEAT_PER_B;
    if (gid >= total) return;
    int b = gid / FEAT_PER_B;
    int r = gid - b * FEAT_PER_B;
    int t = r / 30;
    int c = r - t * 30;
    int bt = b * T + t;
    float v;
    if (c < 10) {
        int ai = atom_i[bt];
        v = (ai != 0) ? emb[ai * NF + c] : 0.0f;
    } else if (c < 20) {
        int aj = atom_j[bt];
        v = (aj != 0) ? emb[aj * NF + (c - 10)] : 0.0f;
    } else {
        int ai = atom_i[bt];
        float d = dist[bt];
        float ctr = (float)(c - 19) * 0.7f;
        float diff = ctr - d;
        v = (ai != 0) ? fexp(-diff * diff) : 0.0f;
    }
    feat[gid] = v;
}

// Kernel 2: GRU recurrence. One wave per block, ONE batch element per wave.
// Lane pair (k, k+32) shares hidden unit k: half p = lane>>5 accumulates
// j = p*15..p*15+14 (hh) and d = p*5..p*5+4 (ih); one shfl_xor(32) butterfly
// combines. Halves weight state to 60 floats/lane -> fits in regs (the R2
// baseline's VGPR=116 < needed 150 showed the compiler was re-loading weights
// from global EVERY step). Grid 2048 -> 2 waves/SIMD for latency hiding.
// __launch_bounds__(64,4): cap at 128 VGPRs.
__launch_bounds__(64, 4)
__global__ void gru_kernel(const float* __restrict__ feat,
                           const float* __restrict__ W_ih,   // [90,10]
                           const float* __restrict__ W_hh,   // [90,30]
                           const float* __restrict__ b_ih,   // [90]
                           const float* __restrict__ b_hh,   // [90]
                           const float* __restrict__ W_out,  // [1,30]
                           const float* __restrict__ b_out,  // [1]
                           float* __restrict__ out) {
    // Double-buffered h, split halves padded to 16 for aligned b128 reads:
    // slots [0..14] = units 0..14, [15] pad, [16..30] = units 15..29, [31] pad.
    __shared__ __align__(16) float hbuf[2][32];
    const int lane = threadIdx.x;
    const int p = lane >> 5;           // which half of the reduction
    const int k = lane & 31;           // hidden unit
    const bool active = (k < HID);
    const int kk = active ? k : (HID - 1);  // clamp; inactive lanes masked later
    const int b = blockIdx.x;
    const int j0 = p * 15;             // my hh column range
    const int d0 = p * 5;              // my ih column range

    // Per-lane weights: 45 hh + 15 ih = 60 VGPRs
    float whh_r[15], whh_z[15], whh_n[15];
#pragma unroll
    for (int jj = 0; jj < 15; ++jj) {
        int j = j0 + jj;
        whh_r[jj] = W_hh[(0 * HID + kk) * HID + j];
        whh_z[jj] = W_hh[(1 * HID + kk) * HID + j];
        whh_n[jj] = W_hh[(2 * HID + kk) * HID + j];
    }
    float wih_r[5], wih_z[5], wih_n[5];
#pragma unroll
    for (int dd = 0; dd < 5; ++dd) {
        int d = d0 + dd;
        wih_r[dd] = W_ih[(0 * HID + kk) * NF + d];
        wih_z[dd] = W_ih[(1 * HID + kk) * NF + d];
        wih_n[dd] = W_ih[(2 * HID + kk) * NF + d];
    }
    const float brz_r = b_ih[0 * HID + kk] + b_hh[0 * HID + kk];
    const float brz_z = b_ih[1 * HID + kk] + b_hh[1 * HID + kk];
    const float bi_n  = b_ih[2 * HID + kk];  // n-gate biases stay split:
    const float bh_n  = b_hh[2 * HID + kk];  // n = tanh(i_n + r*(hh_n + b_hh_n))

    const float* xp = feat + (long)b * FEAT_PER_B + (long)d0 * S3T;

    hbuf[0][lane & 31] = 0.0f;  // zero step-0 read buffer (incl. pad slots)
    __syncthreads();

    float h = 0.0f;
    float xc[5];
#pragma unroll
    for (int dd = 0; dd < 5; ++dd) xc[dd] = xp[dd * S3T];

#pragma unroll 2
    for (int s = 0; s < S3T; ++s) {
        float* rb = hbuf[s & 1];
        float* wb = hbuf[(s + 1) & 1];

        // Prefetch next step's x (stride 6144 B, LLC-resident)
        float xn[5];
        const int sn = (s + 1 < S3T) ? (s + 1) : s;
#pragma unroll
        for (int dd = 0; dd < 5; ++dd) xn[dd] = xp[dd * S3T + sn];

        // h broadcast: 4 x ds_read_b128 (16 floats, 15 used)
        const float4* hv = (const float4*)&rb[p * 16];
        float hj[16];
        *(float4*)&hj[0]  = hv[0];
        *(float4*)&hj[4]  = hv[1];
        *(float4*)&hj[8]  = hv[2];
        *(float4*)&hj[12] = hv[3];

        float ar = 0.0f, az = 0.0f, ani = 0.0f, anh = 0.0f;
#pragma unroll
        for (int dd = 0; dd < 5; ++dd) {
            ar  += wih_r[dd] * xc[dd];
            az  += wih_z[dd] * xc[dd];
            ani += wih_n[dd] * xc[dd];
        }
#pragma unroll
        for (int jj = 0; jj < 15; ++jj) {
            ar  += whh_r[jj] * hj[jj];
            az  += whh_z[jj] * hj[jj];
            anh += whh_n[jj] * hj[jj];
        }
        // combine lane-pair halves (biases added once, after the reduce)
        ar  += __shfl_xor(ar, 32, 64);
        az  += __shfl_xor(az, 32, 64);
        ani += __shfl_xor(ani, 32, 64);
        anh += __shfl_xor(anh, 32, 64);

        float rg = sigmoid_(ar + brz_r);
        float zg = sigmoid_(az + brz_z);
        float ng = tanh_(ani + bi_n + rg * (anh + bh_n));
        h = ng + zg * (h - ng);  // (1-z)*n + z*h

        if (p == 0 && active) wb[(k < 15) ? k : (k + 1)] = h;
        __syncthreads();  // write visible before next step's reads; also
                          // drains this step's rb reads before wb reuse

#pragma unroll
        for (int dd = 0; dd < 5; ++dd) xc[dd] = xn[dd];
    }

    // out[b] = relu(h . W_out + b_out); only p==0,k<30 lanes contribute
    float prod = h * (active ? W_out[kk] : 0.0f);
    float v = (p == 0 && active) ? prod : 0.0f;
#pragma unroll
    for (int off = 32; off; off >>= 1) v += __shfl_xor(v, off, 64);
    if (lane == 0) {
        float o = v + b_out[0];
        out[b] = o > 0.0f ? o : 0.0f;
    }
}

extern "C" void kernel_launch(void* const* d_in, const int* in_sizes, int n_in,
                              void* d_out, int out_size, void* d_ws, size_t ws_size,
                              hipStream_t stream) {
    const int* atom_i   = (const int*)d_in[0];
    const int* atom_j   = (const int*)d_in[1];
    const float* dist   = (const float*)d_in[2];
    const float* emb    = (const float*)d_in[3];
    const float* W_ih   = (const float*)d_in[4];
    const float* W_hh   = (const float*)d_in[5];
    const float* b_ih   = (const float*)d_in[6];
    const float* b_hh   = (const float*)d_in[7];
    const float* W_out  = (const float*)d_in[8];
    const float* b_out  = (const float*)d_in[9];
    float* out = (float*)d_out;
    float* feat = (float*)d_ws;

    const int total = BATCH * FEAT_PER_B;
    const int threads = 256;
    const int blocks = (total + threads - 1) / threads;
    feat_kernel<<<blocks, threads, 0, stream>>>(atom_i, atom_j, dist, emb, feat);
    gru_kernel<<<BATCH, 64, 0, stream>>>(feat, W_ih, W_hh, b_ih, b_hh,
                                         W_out, b_out, out);
}